// Round 1
// baseline (853.690 us; speedup 1.0000x reference)
//
#include <hip/hip_runtime.h>

#define B 256
#define T 2048
#define L 48

// ---------------------------------------------------------------------------
// Kernel A: gold path scores. One block per batch, 256 threads grid-stride
// over T. score_b = sum_t em[b,t,tag] + sum_t trans[tag_t, tag_{t+1}]
//                   + trans[0, tag_0] + trans[tag_{T-1}, L-1]
// Accumulates -score_b into out[0].
// ---------------------------------------------------------------------------
__global__ __launch_bounds__(256) void crf_gold(
    const float* __restrict__ em, const int* __restrict__ tags,
    const float* __restrict__ trans, float* __restrict__ out)
{
    const int b   = blockIdx.x;
    const int tid = threadIdx.x;
    const int*   tg  = tags + (size_t)b * T;
    const float* emb = em   + (size_t)b * T * L;

    float partial = 0.f;
    for (int t = tid; t < T; t += 256) {
        int tag = tg[t];
        partial += emb[t * L + tag];
        if (t + 1 < T) partial += trans[tag * L + tg[t + 1]];
    }
    if (tid == 0)
        partial += trans[tg[0]] + trans[tg[T - 1] * L + (L - 1)];

    // block reduction: wave shuffle + LDS across 4 waves
    #pragma unroll
    for (int off = 32; off; off >>= 1)
        partial += __shfl_xor(partial, off);

    __shared__ float red[4];
    if ((tid & 63) == 0) red[tid >> 6] = partial;
    __syncthreads();
    if (tid == 0) {
        float s = (red[0] + red[1]) + (red[2] + red[3]);
        atomicAdd(out, -s);
    }
}

// ---------------------------------------------------------------------------
// Kernel B: log-partition via forward algorithm. One wave (64 thr) per batch.
// Lane j owns state j (j<48 active). Per step:
//   M  = alpha[lane0]              (shared rescale reference -- exact math)
//   p_j = exp(alpha_j - M)         -> LDS
//   s_j = sum_i p_i * Ecol[i]      (Ecol[i] = exp(trans[i][j]), in regs)
//   alpha_j = M + log(s_j) + em[b,t,j]
// Final: partition_b = logsumexp_j(alpha_j + trans[j][L-1]); atomicAdd to out.
// ---------------------------------------------------------------------------
__global__ __launch_bounds__(64) void crf_forward(
    const float* __restrict__ em, const float* __restrict__ trans,
    float* __restrict__ out)
{
    const int b  = blockIdx.x;
    const int j  = threadIdx.x;
    const int jc = (j < L) ? j : (L - 1);   // clamp for idle lanes 48..63

    __shared__ __align__(16) float p[64];

    // Precompute exp of transition column jc (48 VGPRs / lane).
    float Ecol[L];
    #pragma unroll
    for (int i = 0; i < L; ++i)
        Ecol[i] = __expf(trans[i * L + jc]);

    const float* emb  = em + (size_t)b * T * L;
    const float  tend = trans[jc * L + (L - 1)];

    // t = 0
    float alpha = trans[jc] + emb[jc];

    for (int t = 1; t < T; ++t) {
        float em_t = emb[t * L + jc];           // issued early, hidden by chain
        float M    = __shfl(alpha, 0);
        p[j] = __expf(alpha - M);
        __syncthreads();

        float s0 = 0.f, s1 = 0.f, s2 = 0.f, s3 = 0.f;
        #pragma unroll
        for (int i = 0; i < L; i += 4) {
            float4 pv = *(const float4*)(p + i);
            s0 = fmaf(pv.x, Ecol[i + 0], s0);
            s1 = fmaf(pv.y, Ecol[i + 1], s1);
            s2 = fmaf(pv.z, Ecol[i + 2], s2);
            s3 = fmaf(pv.w, Ecol[i + 3], s3);
        }
        __syncthreads();                         // protect p before next write

        float s = (s0 + s1) + (s2 + s3);
        alpha = M + __logf(s) + em_t;
    }

    // partition_b = logsumexp over active lanes of (alpha + trans[j][L-1])
    float v = (j < L) ? (alpha + tend) : -3.0e38f;
    float m = v;
    #pragma unroll
    for (int off = 32; off; off >>= 1)
        m = fmaxf(m, __shfl_xor(m, off));
    float e = (j < L) ? __expf(v - m) : 0.f;
    #pragma unroll
    for (int off = 32; off; off >>= 1)
        e += __shfl_xor(e, off);

    if (j == 0)
        atomicAdd(out, m + __logf(e));
}

extern "C" void kernel_launch(void* const* d_in, const int* in_sizes, int n_in,
                              void* d_out, int out_size, void* d_ws, size_t ws_size,
                              hipStream_t stream) {
    const float* em    = (const float*)d_in[0];   // (B, T, L) f32
    const int*   tags  = (const int*)  d_in[1];   // (B, T) i32
    const float* trans = (const float*)d_in[2];   // (L, L) f32
    float* out = (float*)d_out;                   // scalar f32

    hipMemsetAsync(out, 0, sizeof(float), stream);
    crf_gold   <<<B, 256, 0, stream>>>(em, tags, trans, out);
    crf_forward<<<B,  64, 0, stream>>>(em, trans, out);
}

// Round 2
// 575.079 us; speedup vs baseline: 1.4845x; 1.4845x over previous
//
#include <hip/hip_runtime.h>

#define B 256
#define T 2048
#define L 48

typedef float v2f __attribute__((ext_vector_type(2)));

// Single-wave workgroup "barrier": drain LDS ops only (lgkmcnt), never vmcnt,
// so global-memory prefetches stay in flight. Memory clobber stops the
// compiler from moving LDS accesses across it. Safe because blockDim == 64.
#define WAVE_SYNC() asm volatile("s_waitcnt lgkmcnt(0)" ::: "memory")

// ---------------------------------------------------------------------------
// Kernel A: gold path scores. Grid = B*4 (each block does a 512-step chunk).
// ---------------------------------------------------------------------------
__global__ __launch_bounds__(256) void crf_gold(
    const float* __restrict__ em, const int* __restrict__ tags,
    const float* __restrict__ trans, float* __restrict__ out)
{
    const int b   = blockIdx.x >> 2;
    const int c   = blockIdx.x & 3;
    const int tid = threadIdx.x;
    const int*   tg  = tags + (size_t)b * T;
    const float* emb = em   + (size_t)b * T * L;

    float partial = 0.f;
    const int t0 = c * 512;
    #pragma unroll
    for (int r = 0; r < 2; ++r) {
        int t   = t0 + r * 256 + tid;
        int tag = tg[t];
        partial += emb[t * L + tag];
        if (t + 1 < T) partial += trans[tag * L + tg[t + 1]];
    }
    if (c == 0 && tid == 0)   partial += trans[tg[0]];
    if (c == 3 && tid == 255) partial += trans[tg[T - 1] * L + (L - 1)];

    #pragma unroll
    for (int off = 32; off; off >>= 1)
        partial += __shfl_xor(partial, off);

    __shared__ float red[4];
    if ((tid & 63) == 0) red[tid >> 6] = partial;
    __syncthreads();
    if (tid == 0) {
        float s = (red[0] + red[1]) + (red[2] + red[3]);
        atomicAdd(out, -s);
    }
}

// ---------------------------------------------------------------------------
// Kernel B: forward algorithm in LINEAR domain with periodic renormalization.
//   a_j ~ exp(alpha_j - logscale);  a'_j = (sum_i a_i * E[i][j]) * exp(em_j)
// E = exp(trans) precomputed in registers (v2f pairs). em prefetched 16 steps
// ahead into a rotating register buffer; g = exp(em) computed off-chain.
// Critical path/step: ds_write -> lgkm wait -> 12x ds_read_b128 -> 24 pk_fma
// -> 1 mul. No exp/log/shfl/barrier on the chain.
// ---------------------------------------------------------------------------
__global__ __launch_bounds__(64) void crf_forward(
    const float* __restrict__ em, const float* __restrict__ trans,
    float* __restrict__ out)
{
    const int b  = blockIdx.x;
    const int j  = threadIdx.x;
    const int jc = (j < L) ? j : (L - 1);

    __shared__ __align__(16) float p[2][64];

    // exp(trans) column jc as 24 packed pairs (rows 2i, 2i+1).
    v2f E2[24];
    #pragma unroll
    for (int i = 0; i < 24; ++i) {
        E2[i].x = __expf(trans[(2 * i    ) * L + jc]);
        E2[i].y = __expf(trans[(2 * i + 1) * L + jc]);
    }
    const float Eend = __expf(trans[jc * L + (L - 1)]);
    const float* emb = em + (size_t)b * T * L;

    float a        = __expf(trans[jc] + emb[jc]);   // t = 0
    float logscale = 0.f;

    // Prefetch blocks 0 (t=1..8) and 1 (t=9..16).
    float bufA[8], bufB[8];
    #pragma unroll
    for (int k = 0; k < 8; ++k) bufA[k] = emb[(1 + k) * L + jc];
    #pragma unroll
    for (int k = 0; k < 8; ++k) bufB[k] = emb[(9 + k) * L + jc];

#define STEP8(buf, blk, NSTEP)                                                \
    {                                                                         \
        float r = __shfl(a, 0);                                               \
        logscale += __logf(r);                                                \
        float rinv = __builtin_amdgcn_rcpf(r);                                \
        float g[8];                                                           \
        _Pragma("unroll")                                                     \
        for (int k = 0; k < 8; ++k) g[k] = __expf(buf[k]);                    \
        _Pragma("unroll")  /* re-issue prefetch for blk+2 (clamped) */        \
        for (int k = 0; k < 8; ++k) {                                         \
            int t  = 1 + 8 * ((blk) + 2) + k;                                 \
            int tt = (t < T) ? t : (T - 1);                                   \
            buf[k] = emb[tt * L + jc];                                        \
        }                                                                     \
        a *= rinv;                                                            \
        _Pragma("unroll")                                                     \
        for (int k = 0; k < (NSTEP); ++k) {                                   \
            p[k & 1][j] = a;                                                  \
            WAVE_SYNC();                                                      \
            const float4* pp = (const float4*)p[k & 1];                       \
            v2f ac0 = {0.f, 0.f}, ac1 = {0.f, 0.f};                           \
            v2f ac2 = {0.f, 0.f}, ac3 = {0.f, 0.f};                           \
            _Pragma("unroll")                                                 \
            for (int i = 0; i < 12; i += 2) {                                 \
                float4 pv = pp[i];                                            \
                v2f x01 = {pv.x, pv.y}, x23 = {pv.z, pv.w};                   \
                ac0 = x01 * E2[2 * i    ] + ac0;                              \
                ac1 = x23 * E2[2 * i + 1] + ac1;                              \
                float4 qv = pp[i + 1];                                        \
                v2f y01 = {qv.x, qv.y}, y23 = {qv.z, qv.w};                   \
                ac2 = y01 * E2[2 * i + 2] + ac2;                              \
                ac3 = y23 * E2[2 * i + 3] + ac3;                              \
            }                                                                 \
            v2f acs = (ac0 + ac1) + (ac2 + ac3);                              \
            a = (acs.x + acs.y) * g[k];                                       \
        }                                                                     \
    }

    // Steps 1..2040: 255 full blocks of 8 (unrolled x2 so buffers stay regs).
    for (int blk = 0; blk < 254; blk += 2) {
        STEP8(bufA, blk,     8);
        STEP8(bufB, blk + 1, 8);
    }
    STEP8(bufA, 254, 8);
    // Tail: steps 2041..2047 (7 steps) from bufB (loaded at blk=253).
    STEP8(bufB, 255, 7);
#undef STEP8

    // partition_b = log(sum_j a_j * Eend_j) + logscale
    float v = (j < L) ? (a * Eend) : 0.f;
    #pragma unroll
    for (int off = 32; off; off >>= 1)
        v += __shfl_xor(v, off);

    if (j == 0)
        atomicAdd(out, __logf(v) + logscale);
}

extern "C" void kernel_launch(void* const* d_in, const int* in_sizes, int n_in,
                              void* d_out, int out_size, void* d_ws, size_t ws_size,
                              hipStream_t stream) {
    const float* em    = (const float*)d_in[0];   // (B, T, L) f32
    const int*   tags  = (const int*)  d_in[1];   // (B, T) i32
    const float* trans = (const float*)d_in[2];   // (L, L) f32
    float* out = (float*)d_out;                   // scalar f32

    hipMemsetAsync(out, 0, sizeof(float), stream);
    crf_gold   <<<B * 4, 256, 0, stream>>>(em, tags, trans, out);
    crf_forward<<<B,      64, 0, stream>>>(em, trans, out);
}

// Round 3
// 360.360 us; speedup vs baseline: 2.3690x; 1.5958x over previous
//
#include <hip/hip_runtime.h>

#define B 256
#define T 2048
#define L 48

// Broadcast lane `lane`'s value of v to all lanes via v_readlane -> SGPR.
// Result is wave-uniform (lives in an SGPR), so the consuming v_fma uses it
// as its one legal scalar operand -- no LDS, no ds_bpermute, no latency.
__device__ __forceinline__ float bcast(float v, int lane) {
    return __int_as_float(__builtin_amdgcn_readlane(__float_as_int(v), lane));
}

// ---------------------------------------------------------------------------
// Half-chain scan in the linear domain with periodic renorm.
//  fwd (BWD=0): a_j' = (sum_i a_i E[i][j]) * g_j,  g = exp(em[t,:]),  t: 1..1023
//  bwd (BWD=1): b_i' = sum_j E[i][j] * (g_j b_j),  g = exp(em[t+1,:]), t: 2046..1023
// Critical path/step: 48 readlane + 48 fmac (+1 mul) -- pure VALU, ~200 cyc.
// Stores state vector (48) + logscale to ws; also computes this half's gold
// score contribution (fused, off the critical path).
// ---------------------------------------------------------------------------
template<bool BWD>
__device__ __forceinline__ void scan_body(
    int b, int j, const float* __restrict__ em, const int* __restrict__ tags,
    const float* __restrict__ trans, float* __restrict__ out, float* __restrict__ ws)
{
    const int jc = (j < L) ? j : (L - 1);
    const float* emb = em + (size_t)b * T * L;

    // fwd lane j holds column j of E=exp(trans); bwd lane i holds row i.
    float E[L];
    #pragma unroll
    for (int i = 0; i < L; ++i)
        E[i] = __expf(BWD ? trans[jc * L + i] : trans[i * L + jc]);

    constexpr int NS    = BWD ? 1024 : 1023;  // recursion steps
    constexpr int dstep = BWD ? -L : L;       // em row stride per step

    float a, logscale = 0.f;
    if (BWD) a = __expf(trans[jc * L + (L - 1)]);     // beta_{T-1} = E[:,end]
    else     a = __expf(trans[jc] + emb[jc]);         // alpha_0

    // em for step s lives at row (BWD ? T-s : s). Prefetch 16 steps deep.
    const float* p0 = emb + (BWD ? (T - 1) : 1) * L + jc;
    float bufA[8], bufB[8];
    #pragma unroll
    for (int k = 0; k < 8; ++k) bufA[k] = p0[k * dstep];
    #pragma unroll
    for (int k = 0; k < 8; ++k) bufB[k] = p0[(8 + k) * dstep];
    const float* pf = p0 + 16 * dstep;   // prefetch cursor (step 17)
    // NOTE: tail prefetches overrun by <=16 steps but stay inside this
    // batch's em rows (t in [0,2047]) -- valid loads, values unused.

#define STEP8(buf, NSTEP)                                                     \
    {                                                                         \
        float r = bcast(a, 0);                   /* renorm vs lane 0 */       \
        logscale += __logf(r);                                                \
        float rinv = __builtin_amdgcn_rcpf(r);                                \
        float g[8];                                                           \
        _Pragma("unroll")                                                     \
        for (int k = 0; k < 8; ++k) g[k] = __expf(buf[k]);                    \
        _Pragma("unroll")                                                     \
        for (int k = 0; k < 8; ++k) buf[k] = pf[k * dstep];                   \
        pf += 8 * dstep;                                                      \
        a *= rinv;                                                            \
        _Pragma("unroll")                                                     \
        for (int k = 0; k < (NSTEP); ++k) {                                   \
            float v = BWD ? a * g[k] : a;                                     \
            float c0 = 0.f, c1 = 0.f, c2 = 0.f, c3 = 0.f;                     \
            _Pragma("unroll")                                                 \
            for (int i = 0; i < L; i += 4) {                                  \
                c0 = fmaf(bcast(v, i + 0), E[i + 0], c0);                     \
                c1 = fmaf(bcast(v, i + 1), E[i + 1], c1);                     \
                c2 = fmaf(bcast(v, i + 2), E[i + 2], c2);                     \
                c3 = fmaf(bcast(v, i + 3), E[i + 3], c3);                     \
            }                                                                 \
            float s = (c0 + c1) + (c2 + c3);                                  \
            a = BWD ? s : s * g[k];                                           \
        }                                                                     \
    }

    if (BWD) {
        for (int blk = 0; blk < 128; blk += 2) { STEP8(bufA, 8); STEP8(bufB, 8); }
    } else {
        for (int blk = 0; blk < 126; blk += 2) { STEP8(bufA, 8); STEP8(bufB, 8); }
        STEP8(bufA, 8);     // steps 1009..1016
        STEP8(bufB, 7);     // steps 1017..1023
    }
#undef STEP8

    // Store half-chain state for the combine kernel.
    float* w = ws + (size_t)(2 * b + (BWD ? 1 : 0)) * 64;
    if (j < L)  w[j] = a;
    if (j == 0) w[L] = logscale;

    // ---- fused gold score for this half's t-range (off critical path) ----
    const int* tg = tags + (size_t)b * T;
    const int  t0 = BWD ? (T / 2) : 0;
    float gp = 0.f;
    #pragma unroll
    for (int r = 0; r < 16; ++r) {
        int t   = t0 + r * 64 + j;
        int tag = tg[t];
        gp += emb[t * L + tag];
        if (t < T - 1) gp += trans[tag * L + tg[t + 1]];
    }
    if (!BWD && j == 0)  gp += trans[tg[0]];                 // start
    if ( BWD && j == 63) gp += trans[tg[T - 1] * L + (L - 1)]; // end
    #pragma unroll
    for (int off = 32; off; off >>= 1) gp += __shfl_xor(gp, off);
    if (j == 0) atomicAdd(out, -gp);
}

__global__ __launch_bounds__(64) void crf_scan(
    const float* __restrict__ em, const int* __restrict__ tags,
    const float* __restrict__ trans, float* __restrict__ out, float* __restrict__ ws)
{
    const int blk = blockIdx.x;
    const int b   = blk & (B - 1);
    const int j   = threadIdx.x;
    if (blk < B) scan_body<false>(b, j, em, tags, trans, out, ws);
    else         scan_body<true >(b, j, em, tags, trans, out, ws);
}

// ---------------------------------------------------------------------------
// Combine: Z_b = log(sum_j fwd_j * bwd_j) + scale_f + scale_b, max-normalized
// so the product can't overflow fp32.
// ---------------------------------------------------------------------------
__global__ __launch_bounds__(64) void crf_combine(
    const float* __restrict__ ws, float* __restrict__ out)
{
    const int b = blockIdx.x, j = threadIdx.x;
    const float* F  = ws + (size_t)(2 * b) * 64;
    const float* Bw = ws + (size_t)(2 * b + 1) * 64;

    float f = (j < L) ? F[j]  : 0.f;
    float g = (j < L) ? Bw[j] : 0.f;
    float mf = f, mg = g;
    #pragma unroll
    for (int off = 32; off; off >>= 1) {
        mf = fmaxf(mf, __shfl_xor(mf, off));
        mg = fmaxf(mg, __shfl_xor(mg, off));
    }
    float x = (f / mf) * (g / mg);
    #pragma unroll
    for (int off = 32; off; off >>= 1) x += __shfl_xor(x, off);

    if (j == 0)
        atomicAdd(out, __logf(x) + __logf(mf) + __logf(mg) + F[L] + Bw[L]);
}

extern "C" void kernel_launch(void* const* d_in, const int* in_sizes, int n_in,
                              void* d_out, int out_size, void* d_ws, size_t ws_size,
                              hipStream_t stream) {
    const float* em    = (const float*)d_in[0];   // (B, T, L) f32
    const int*   tags  = (const int*)  d_in[1];   // (B, T) i32
    const float* trans = (const float*)d_in[2];   // (L, L) f32
    float* out = (float*)d_out;
    float* ws  = (float*)d_ws;                    // needs 512*64*4 = 128 KB

    hipMemsetAsync(out, 0, sizeof(float), stream);
    crf_scan   <<<2 * B, 64, 0, stream>>>(em, tags, trans, out, ws);
    crf_combine<<<B,     64, 0, stream>>>(ws, out);
}

// Round 4
// 320.963 us; speedup vs baseline: 2.6598x; 1.1227x over previous
//
#include <hip/hip_runtime.h>

#define B 256
#define T 2048
#define L 48
#define G 8            // segments per batch chain
#define SEG 256        // max steps per segment
#define QSTRIDE 2308   // floats per segment record in ws (2304 Q + logscale)
#define TOTALF (B * T * L)

typedef short v4s __attribute__((ext_vector_type(4)));
typedef float v4f __attribute__((ext_vector_type(4)));
typedef int   v2i __attribute__((ext_vector_type(2)));

// Single-wave "barrier": drain LDS counters only; never vmcnt.
#define WAVE_SYNC() asm volatile("s_waitcnt lgkmcnt(0)" ::: "memory")

#if __has_builtin(__builtin_amdgcn_mfma_f32_16x16x16bf16_1k)
#define MFMA16(a, b, c) __builtin_amdgcn_mfma_f32_16x16x16bf16_1k((a), (b), (c), 0, 0, 0)
#else
__device__ __forceinline__ v4f mfma16_asm(v4s a, v4s b, v4f c) {
    asm volatile("v_mfma_f32_16x16x16_bf16 %0, %1, %2, %0\n\ts_nop 7\n\ts_nop 7"
                 : "+v"(c) : "v"(a), "v"(b));
    return c;
}
#define MFMA16(a, b, c) mfma16_asm((a), (b), (c))
#endif

// (bf16(hi) << 16) | bf16(lo), round-half-up via +0x8000 then take high 16.
__device__ __forceinline__ unsigned pack_bf16(float hi, float lo) {
    unsigned uh = __float_as_uint(hi) + 0x8000u;
    unsigned ul = __float_as_uint(lo) + 0x8000u;
    return __builtin_amdgcn_perm(uh, ul, 0x07060302u);
}
__device__ __forceinline__ v4s pack4_bf16(v4f v) {
    v2i d;
    d.x = (int)pack_bf16(v.y, v.x);
    d.y = (int)pack_bf16(v.w, v.z);
    return __builtin_bit_cast(v4s, d);
}

// ---------------------------------------------------------------------------
// Segment scan: wave (b,s) computes Q_s = prod_{t=te..ts} D(g_t) E^T  (48x48)
// via 27 MFMA(16x16x16 bf16)/step. D-layout == B-layout => no cross-lane
// shuffle between steps. Renorm every 4 steps by C[0][0] (readfirstlane).
// Also computes this segment's gold-score contribution (fused, after scan).
// ---------------------------------------------------------------------------
__global__ __launch_bounds__(64, 2) void crf_scan(
    const float* __restrict__ em, const int* __restrict__ tags,
    const float* __restrict__ trans, float* __restrict__ out,
    float* __restrict__ ws)
{
    const int b = blockIdx.x >> 3;
    const int s = blockIdx.x & 7;
    const int j = threadIdx.x;
    const int q = j >> 4;          // 0..3
    const int c = j & 15;          // 0..15

    __shared__ __align__(16) float smem[2 * 384];   // 8 em rows x 2 buffers

    const size_t bem = (size_t)b * T * L;
    const int t0 = 1 + SEG * s;
    const int t1 = (t0 + SEG < T) ? (t0 + SEG) : T;   // s=7 -> 255 steps

    // --- constant A fragments: E^T[i][k] = exp(trans[k][i]) ---------------
    // A layout: row = c (lane&15), k = 4q + e.  Tile (rt, kt).
    v4s Af[3][3];
    #pragma unroll
    for (int rt = 0; rt < 3; ++rt)
        #pragma unroll
        for (int kt = 0; kt < 3; ++kt) {
            v4f e;
            #pragma unroll
            for (int ee = 0; ee < 4; ++ee)
                e[ee] = __expf(trans[(16 * kt + 4 * q + ee) * L + 16 * rt + c]);
            Af[rt][kt] = pack4_bf16(e);
        }

    // --- state Q as B fragments: Q[k][col], k = 4q+e, col = c. Init I. ----
    v4s Bq[3][3];
    #pragma unroll
    for (int kt = 0; kt < 3; ++kt)
        #pragma unroll
        for (int ct = 0; ct < 3; ++ct) {
            v2i d;
            int k0 = 16 * kt + 4 * q, col = 16 * ct + c;
            d.x = (k0 + 0 == col ? 0x3F80 : 0) | (k0 + 1 == col ? 0x3F800000 : 0);
            d.y = (k0 + 2 == col ? 0x3F80 : 0) | (k0 + 3 == col ? 0x3F800000 : 0);
            Bq[kt][ct] = __builtin_bit_cast(v4s, d);
        }

    v4f Cf[3][3];          // fp32 scaled result (persists; stored at end)
    float logscale = 0.f;

    // --- stage em rows t0..t0+7 into buffer 0 -----------------------------
    {
        size_t gf = bem + (size_t)t0 * L;
        #pragma unroll
        for (int ch = 0; ch < 6; ++ch)
            smem[64 * ch + j] = em[gf + 64 * ch + j];
        WAVE_SYNC();
    }

    auto do_step = [&](const float* rowp, bool renorm) {
        // C = E^T x Q
        #pragma unroll
        for (int rt = 0; rt < 3; ++rt)
            #pragma unroll
            for (int ct = 0; ct < 3; ++ct) {
                v4f acc = {0.f, 0.f, 0.f, 0.f};
                acc = MFMA16(Af[rt][0], Bq[0][ct], acc);
                acc = MFMA16(Af[rt][1], Bq[1][ct], acc);
                acc = MFMA16(Af[rt][2], Bq[2][ct], acc);
                Cf[rt][ct] = acc;
            }
        // g for rows 16rt + 4q + e  (C/D row index)
        v4f gv[3];
        #pragma unroll
        for (int rt = 0; rt < 3; ++rt) {
            v4f ev = *(const v4f*)(rowp + 16 * rt + 4 * q);
            #pragma unroll
            for (int ee = 0; ee < 4; ++ee) gv[rt][ee] = __expf(ev[ee]);
        }
        if (renorm) {
            float r = __int_as_float(
                __builtin_amdgcn_readfirstlane(__float_as_int(Cf[0][0].x)));
            logscale += __logf(r);
            float ri = __builtin_amdgcn_rcpf(r);
            #pragma unroll
            for (int rt = 0; rt < 3; ++rt)
                #pragma unroll
                for (int ee = 0; ee < 4; ++ee) gv[rt][ee] *= ri;
        }
        // Q_new = D(g) C : row scale, then fp32 -> bf16 B frags (row == k).
        #pragma unroll
        for (int rt = 0; rt < 3; ++rt)
            #pragma unroll
            for (int ct = 0; ct < 3; ++ct) {
                Cf[rt][ct] *= gv[rt];
                Bq[rt][ct] = pack4_bf16(Cf[rt][ct]);
            }
    };

    // --- main loop: 32 blocks of 8 steps, LDS double-buffered -------------
    for (int bk = 0; bk < 32; ++bk) {
        const float* cur = smem + (bk & 1) * 384;
        float* nxt = smem + ((bk & 1) ^ 1) * 384;

        // prefetch next 8 rows (clamped at array end; overrun rows unused)
        size_t gf = bem + (size_t)(t0 + 8 * (bk + 1)) * L;
        if (gf > (size_t)TOTALF - 384) gf = (size_t)TOTALF - 384;
        float stg[6];
        #pragma unroll
        for (int ch = 0; ch < 6; ++ch) stg[ch] = em[gf + 64 * ch + j];

        #pragma unroll
        for (int k = 0; k < 8; ++k)
            if (t0 + 8 * bk + k < t1)          // wave-uniform guard
                do_step(cur + 48 * k, (k & 3) == 0);

        #pragma unroll
        for (int ch = 0; ch < 6; ++ch) nxt[64 * ch + j] = stg[ch];
        WAVE_SYNC();
    }

    // --- store Q (fp32, row-major) + logscale -----------------------------
    float* qb = ws + (size_t)(b * G + s) * QSTRIDE;
    #pragma unroll
    for (int rt = 0; rt < 3; ++rt)
        #pragma unroll
        for (int ct = 0; ct < 3; ++ct)
            #pragma unroll
            for (int ee = 0; ee < 4; ++ee)
                qb[(16 * rt + 4 * q + ee) * L + 16 * ct + c] = Cf[rt][ct][ee];
    if (j == 0) qb[2304] = logscale;

    // --- fused gold score: t in [256 s, 256 s + 256) ----------------------
    const int* tg = tags + (size_t)b * T;
    float gp = 0.f;
    #pragma unroll
    for (int r = 0; r < 4; ++r) {
        int t = SEG * s + 64 * r + j;
        int tag = tg[t];
        gp += em[bem + (size_t)t * L + tag];
        if (t < T - 1) gp += trans[tag * L + tg[t + 1]];
        if (t == 0)     gp += trans[tag];
        if (t == T - 1) gp += trans[tag * L + (L - 1)];
    }
    #pragma unroll
    for (int off = 32; off; off >>= 1) gp += __shfl_xor(gp, off);
    if (j == 0) atomicAdd(out, -gp);
}

// ---------------------------------------------------------------------------
// Combine: per batch, u = alpha_0; for s: u = Q_s u (renormed); then
// Z_b = log(sum_i u_i exp(trans[i][L-1])) + accumulated logscales.
// ---------------------------------------------------------------------------
__global__ __launch_bounds__(64) void crf_combine(
    const float* __restrict__ em, const float* __restrict__ trans,
    const float* __restrict__ ws, float* __restrict__ out)
{
    const int b = blockIdx.x, l = threadIdx.x;
    const int lc = (l < L) ? l : (L - 1);

    __shared__ __align__(16) float Qs[48 * 52];
    __shared__ __align__(16) float us[64];

    float u = (l < L) ? __expf(trans[l] + em[(size_t)b * T * L + l]) : 0.f;
    float logtot = 0.f;

    for (int s = 0; s < G; ++s) {
        const float* qb = ws + (size_t)(b * G + s) * QSTRIDE;
        #pragma unroll
        for (int r = 0; r < 36; ++r) {
            int flat = r * 64 + l;
            int row = flat / 48, col = flat - row * 48;
            Qs[row * 52 + col] = qb[flat];
        }
        us[l] = u;
        WAVE_SYNC();

        float acc = 0.f;
        const v4f* qrow = (const v4f*)(Qs + lc * 52);
        const v4f* urow = (const v4f*)us;
        #pragma unroll
        for (int jj = 0; jj < 12; ++jj) {
            v4f qv = qrow[jj], uv = urow[jj];
            acc = fmaf(qv.x, uv.x, acc);
            acc = fmaf(qv.y, uv.y, acc);
            acc = fmaf(qv.z, uv.z, acc);
            acc = fmaf(qv.w, uv.w, acc);
        }
        WAVE_SYNC();   // reads done before next iteration's writes

        float rs = __shfl(acc, 0);
        logtot += __logf(rs) + qb[2304];
        u = (l < L) ? acc * __builtin_amdgcn_rcpf(rs) : 0.f;
    }

    float v = (l < L) ? u * __expf(trans[lc * L + (L - 1)]) : 0.f;
    #pragma unroll
    for (int off = 32; off; off >>= 1) v += __shfl_xor(v, off);
    if (l == 0) atomicAdd(out, logtot + __logf(v));
}

extern "C" void kernel_launch(void* const* d_in, const int* in_sizes, int n_in,
                              void* d_out, int out_size, void* d_ws, size_t ws_size,
                              hipStream_t stream) {
    const float* em    = (const float*)d_in[0];   // (B, T, L) f32
    const int*   tags  = (const int*)  d_in[1];   // (B, T) i32
    const float* trans = (const float*)d_in[2];   // (L, L) f32
    float* out = (float*)d_out;
    float* ws  = (float*)d_ws;                    // needs 2048*2308*4 = 18.9 MB

    hipMemsetAsync(out, 0, sizeof(float), stream);
    crf_scan   <<<B * G, 64, 0, stream>>>(em, tags, trans, out, ws);
    crf_combine<<<B,     64, 0, stream>>>(em, trans, ws, out);
}

// Round 6
// 282.381 us; speedup vs baseline: 3.0232x; 1.1366x over previous
//
#include <hip/hip_runtime.h>

#define B 256
#define T 2048
#define L 48
#define G 16           // segments per batch chain
#define SEG 128        // steps per segment (last: 127)
#define KNORM 4.371f   // per-step constant renorm: ln(48*e^0.5)
#define TOTALF (B * T * L)

typedef short v4s __attribute__((ext_vector_type(4)));
typedef float v4f __attribute__((ext_vector_type(4)));
typedef int   v2i __attribute__((ext_vector_type(2)));

// Single-wave "barrier": drain LDS counters only; never vmcnt.
#define WAVE_SYNC() asm volatile("s_waitcnt lgkmcnt(0)" ::: "memory")

#if __has_builtin(__builtin_amdgcn_mfma_f32_16x16x16bf16_1k)
#define MFMA16(a, b, c) __builtin_amdgcn_mfma_f32_16x16x16bf16_1k((a), (b), (c), 0, 0, 0)
#else
__device__ __forceinline__ v4f mfma16_asm(v4s a, v4s b, v4f c) {
    asm volatile("v_mfma_f32_16x16x16_bf16 %0, %1, %2, %0\n\ts_nop 7\n\ts_nop 7"
                 : "+v"(c) : "v"(a), "v"(b));
    return c;
}
#define MFMA16(a, b, c) mfma16_asm((a), (b), (c))
#endif

// pack two fp32 -> (bf16(hi)<<16)|bf16(lo)
__device__ __forceinline__ unsigned pk_bf16(float lo, float hi) {
#if __has_builtin(__builtin_amdgcn_cvt_pk_bf16_f32)
    auto r = __builtin_amdgcn_cvt_pk_bf16_f32(lo, hi);   // HW RNE pack (gfx950)
    unsigned u;
    __builtin_memcpy(&u, &r, 4);
    return u;
#else
    unsigned uh = __float_as_uint(hi) + 0x8000u;         // round-half-up
    unsigned ul = __float_as_uint(lo) + 0x8000u;
    return __builtin_amdgcn_perm(uh, ul, 0x07060302u);
#endif
}

// (C .* g) rounded to bf16 B-fragment
__device__ __forceinline__ v4s scale_pack(v4f cf, v4f g) {
    float a0 = cf.x * g.x, a1 = cf.y * g.y;
    float a2 = cf.z * g.z, a3 = cf.w * g.w;
    v2i d;
    d.x = (int)pk_bf16(a0, a1);
    d.y = (int)pk_bf16(a2, a3);
    return __builtin_bit_cast(v4s, d);
}

// ---------------------------------------------------------------------------
// Segment scan: wave (b,s) computes Q_s = prod_t [D(g_t) E^T / e^K]  (48x48)
// via 27 MFMA(16x16x16 bf16)/step.  g_t = exp(em_t - K) precomputed in LDS
// during staging.  C/D layout == B layout => result feeds next step with no
// cross-lane movement.  No adaptive renorm on the chain (constant e^-K).
// Final Q stored bf16 row-major; gold-score contribution fused at the end.
// ---------------------------------------------------------------------------
__global__ __launch_bounds__(64, 4) void crf_scan(
    const float* __restrict__ em, const int* __restrict__ tags,
    const float* __restrict__ trans, float* __restrict__ out,
    float* __restrict__ ws)
{
    const int b = blockIdx.x >> 4;
    const int s = blockIdx.x & 15;
    const int j = threadIdx.x;
    const int q = j >> 4;          // 0..3
    const int c = j & 15;          // 0..15

    __shared__ __align__(16) float smem[2 * 384];   // 8 g-rows x 2 buffers

    const size_t bem = (size_t)b * T * L;
    const int t0 = 1 + SEG * s;
    const int t1 = (t0 + SEG < T) ? (t0 + SEG) : T;   // s=15 -> 127 steps

    // A fragments: E^T tile (rt,kt): A[m=c][k=4q+e] = exp(trans[k_glob][m_glob])
    v4s Af[3][3];
    #pragma unroll
    for (int rt = 0; rt < 3; ++rt)
        #pragma unroll
        for (int kt = 0; kt < 3; ++kt) {
            v4f e;
            #pragma unroll
            for (int ee = 0; ee < 4; ++ee)
                e[ee] = __expf(trans[(16 * kt + 4 * q + ee) * L + 16 * rt + c]);
            Af[rt][kt] = scale_pack(e, v4f{1.f, 1.f, 1.f, 1.f});
        }

    // State Q as B fragments: Q[k=4q+e][col=c]. Init identity.
    v4s Bq[3][3];
    #pragma unroll
    for (int kt = 0; kt < 3; ++kt)
        #pragma unroll
        for (int ct = 0; ct < 3; ++ct) {
            v2i d;
            int k0 = 16 * kt + 4 * q, col = 16 * ct + c;
            d.x = (k0 + 0 == col ? 0x3F80 : 0) | (k0 + 1 == col ? 0x3F800000 : 0);
            d.y = (k0 + 2 == col ? 0x3F80 : 0) | (k0 + 3 == col ? 0x3F800000 : 0);
            Bq[kt][ct] = __builtin_bit_cast(v4s, d);
        }

    auto do_step = [&](const float* rowp) {
        v4f gv[3];
        #pragma unroll
        for (int rt = 0; rt < 3; ++rt)
            gv[rt] = *(const v4f*)(rowp + 16 * rt + 4 * q);
        v4s Bn[3][3];
        #pragma unroll
        for (int rt = 0; rt < 3; ++rt)
            #pragma unroll
            for (int ct = 0; ct < 3; ++ct) {
                v4f acc = {0.f, 0.f, 0.f, 0.f};
                acc = MFMA16(Af[rt][0], Bq[0][ct], acc);
                acc = MFMA16(Af[rt][1], Bq[1][ct], acc);
                acc = MFMA16(Af[rt][2], Bq[2][ct], acc);
                Bn[rt][ct] = scale_pack(acc, gv[rt]);   // row-scale by g, pack
            }
        #pragma unroll
        for (int rt = 0; rt < 3; ++rt)
            #pragma unroll
            for (int ct = 0; ct < 3; ++ct)
                Bq[rt][ct] = Bn[rt][ct];
    };

    // stage g-rows t0..t0+7 into buffer 0
    {
        size_t gf = bem + (size_t)t0 * L;
        #pragma unroll
        for (int ch = 0; ch < 6; ++ch)
            smem[64 * ch + j] = __expf(em[gf + 64 * ch + j] - KNORM);
        WAVE_SYNC();
    }

    for (int bk = 0; bk < 16; ++bk) {
        const float* cur = smem + (bk & 1) * 384;
        float* nxt = smem + ((bk & 1) ^ 1) * 384;

        size_t gf = bem + (size_t)(t0 + 8 * (bk + 1)) * L;
        if (gf > (size_t)TOTALF - 384) gf = (size_t)TOTALF - 384;
        float stg[6];
        #pragma unroll
        for (int ch = 0; ch < 6; ++ch) stg[ch] = em[gf + 64 * ch + j];

        #pragma unroll
        for (int k = 0; k < 8; ++k)
            if (t0 + 8 * bk + k < t1)            // wave-uniform guard
                do_step(cur + 48 * k);

        #pragma unroll
        for (int ch = 0; ch < 6; ++ch)
            nxt[64 * ch + j] = __expf(stg[ch] - KNORM);
        WAVE_SYNC();
    }

    // store Q as bf16 row-major [row*48+col]
    unsigned short* qs = (unsigned short*)ws + (size_t)(b * G + s) * 2304;
    #pragma unroll
    for (int kt = 0; kt < 3; ++kt)
        #pragma unroll
        for (int ct = 0; ct < 3; ++ct) {
            v2i d = __builtin_bit_cast(v2i, Bq[kt][ct]);
            int r0 = 16 * kt + 4 * q, col = 16 * ct + c;
            qs[(r0 + 0) * 48 + col] = (unsigned short)((unsigned)d.x & 0xffffu);
            qs[(r0 + 1) * 48 + col] = (unsigned short)((unsigned)d.x >> 16);
            qs[(r0 + 2) * 48 + col] = (unsigned short)((unsigned)d.y & 0xffffu);
            qs[(r0 + 3) * 48 + col] = (unsigned short)((unsigned)d.y >> 16);
        }

    // fused gold score for t in [128 s, 128 s + 128)
    const int* tg = tags + (size_t)b * T;
    float gp = 0.f;
    #pragma unroll
    for (int r = 0; r < 2; ++r) {
        int t = SEG * s + 64 * r + j;
        int tag = tg[t];
        gp += em[bem + (size_t)t * L + tag];
        if (t < T - 1)  gp += trans[tag * L + tg[t + 1]];
        if (t == 0)     gp += trans[tag];
        if (t == T - 1) gp += trans[tag * L + (L - 1)];
    }
    #pragma unroll
    for (int off = 32; off; off >>= 1) gp += __shfl_xor(gp, off);
    if (j == 0) atomicAdd(out, -gp);
}

// ---------------------------------------------------------------------------
// Combine: per batch, u = alpha_0; for s: u = Q_s u (renormed, bf16 rows,
// next-segment register prefetch); Z_b = log(sum u_i E[i][end]) + 2047*K +
// accumulated renorm logs.  Lane l owns row l => no cross-lane reduce.
// ---------------------------------------------------------------------------
__global__ __launch_bounds__(64) void crf_combine(
    const float* __restrict__ em, const float* __restrict__ trans,
    const float* __restrict__ ws, float* __restrict__ out)
{
    const int b = blockIdx.x, l = threadIdx.x;
    const int lc = (l < L) ? l : (L - 1);

    __shared__ float us[64];

    const unsigned short* qb = (const unsigned short*)ws + (size_t)b * G * 2304;

    float u = (l < L) ? __expf(trans[l] + em[(size_t)b * T * L + l]) : 0.f;
    float logtot = 2047.0f * KNORM;

    uint4 pre[6];
    {
        const uint4* p = (const uint4*)(qb + lc * 48);
        #pragma unroll
        for (int ii = 0; ii < 6; ++ii) pre[ii] = p[ii];
    }

    for (int s = 0; s < G; ++s) {
        us[l] = u;
        uint4 cur[6];
        #pragma unroll
        for (int ii = 0; ii < 6; ++ii) cur[ii] = pre[ii];
        if (s + 1 < G) {
            const uint4* p = (const uint4*)(qb + (size_t)(s + 1) * 2304 + lc * 48);
            #pragma unroll
            for (int ii = 0; ii < 6; ++ii) pre[ii] = p[ii];
        }
        WAVE_SYNC();

        float acc = 0.f;
        #pragma unroll
        for (int ii = 0; ii < 6; ++ii) {
            unsigned w0 = cur[ii].x, w1 = cur[ii].y, w2 = cur[ii].z, w3 = cur[ii].w;
            int jj = ii * 8;
            acc = fmaf(__uint_as_float(w0 << 16),          us[jj + 0], acc);
            acc = fmaf(__uint_as_float(w0 & 0xffff0000u),  us[jj + 1], acc);
            acc = fmaf(__uint_as_float(w1 << 16),          us[jj + 2], acc);
            acc = fmaf(__uint_as_float(w1 & 0xffff0000u),  us[jj + 3], acc);
            acc = fmaf(__uint_as_float(w2 << 16),          us[jj + 4], acc);
            acc = fmaf(__uint_as_float(w2 & 0xffff0000u),  us[jj + 5], acc);
            acc = fmaf(__uint_as_float(w3 << 16),          us[jj + 6], acc);
            acc = fmaf(__uint_as_float(w3 & 0xffff0000u),  us[jj + 7], acc);
        }
        WAVE_SYNC();   // us reads done before next overwrite

        float r = __int_as_float(
            __builtin_amdgcn_readlane(__float_as_int(acc), 0));
        logtot += __logf(r);
        u = (l < L) ? acc * __builtin_amdgcn_rcpf(r) : 0.f;
    }

    float v = (l < L) ? u * __expf(trans[lc * L + (L - 1)]) : 0.f;
    #pragma unroll
    for (int off = 32; off; off >>= 1) v += __shfl_xor(v, off);
    if (l == 0) atomicAdd(out, logtot + __logf(v));
}

extern "C" void kernel_launch(void* const* d_in, const int* in_sizes, int n_in,
                              void* d_out, int out_size, void* d_ws, size_t ws_size,
                              hipStream_t stream) {
    const float* em    = (const float*)d_in[0];   // (B, T, L) f32
    const int*   tags  = (const int*)  d_in[1];   // (B, T) i32
    const float* trans = (const float*)d_in[2];   // (L, L) f32
    float* out = (float*)d_out;
    float* ws  = (float*)d_ws;                    // 4096 * 2304 bf16 = 18.9 MB

    (void)hipMemsetAsync(out, 0, sizeof(float), stream);
    crf_scan   <<<B * G, 64, 0, stream>>>(em, tags, trans, out, ws);
    crf_combine<<<B,     64, 0, stream>>>(em, trans, ws, out);
}

// Round 7
// 267.591 us; speedup vs baseline: 3.1903x; 1.0553x over previous
//
#include <hip/hip_runtime.h>

#define B 256
#define T 2048
#define L 48
#define G 16           // segments per batch chain
#define SEG 128        // steps per segment (last: 127)
#define KNORM 4.371f   // per-step constant renorm: ln(48*e^0.5)
#define TOTALF (B * T * L)

typedef short v4s __attribute__((ext_vector_type(4)));
typedef float v4f __attribute__((ext_vector_type(4)));
typedef int   v2i __attribute__((ext_vector_type(2)));

// Single-wave "barrier" (combine kernel only): drain LDS counters, not vmcnt.
#define WAVE_SYNC() asm volatile("s_waitcnt lgkmcnt(0)" ::: "memory")

#if __has_builtin(__builtin_amdgcn_mfma_f32_16x16x16bf16_1k)
#define MFMA16(a, b, c) __builtin_amdgcn_mfma_f32_16x16x16bf16_1k((a), (b), (c), 0, 0, 0)
#else
__device__ __forceinline__ v4f mfma16_asm(v4s a, v4s b, v4f c) {
    asm volatile("v_mfma_f32_16x16x16_bf16 %0, %1, %2, %0\n\ts_nop 7\n\ts_nop 7"
                 : "+v"(c) : "v"(a), "v"(b));
    return c;
}
#define MFMA16(a, b, c) mfma16_asm((a), (b), (c))
#endif

// pack two fp32 -> (bf16(hi)<<16)|bf16(lo)
__device__ __forceinline__ unsigned pk_bf16(float lo, float hi) {
#if __has_builtin(__builtin_amdgcn_cvt_pk_bf16_f32)
    auto r = __builtin_amdgcn_cvt_pk_bf16_f32(lo, hi);   // HW RNE pack (gfx950)
    unsigned u;
    __builtin_memcpy(&u, &r, 4);
    return u;
#else
    unsigned uh = __float_as_uint(hi) + 0x8000u;         // round-half-up
    unsigned ul = __float_as_uint(lo) + 0x8000u;
    return __builtin_amdgcn_perm(uh, ul, 0x07060302u);
#endif
}

// (C .* g) rounded to bf16 fragment
__device__ __forceinline__ v4s scale_pack(v4f cf, v4f g) {
    float a0 = cf.x * g.x, a1 = cf.y * g.y;
    float a2 = cf.z * g.z, a3 = cf.w * g.w;
    v2i d;
    d.x = (int)pk_bf16(a0, a1);
    d.y = (int)pk_bf16(a2, a3);
    return __builtin_bit_cast(v4s, d);
}

// ---------------------------------------------------------------------------
// Segment scan, column-split: workgroup (b,s) = 192 threads = 3 waves; wave w
// owns 16-column slice ct=w of Q_s = prod_t [D(g_t) E^T / e^K].  Columns of Q
// evolve independently, so waves never exchange state.  Per wave per step:
// 9 MFMA(16x16x16 bf16) + row-scale by g + bf16 pack.  C/D layout == B layout
// => zero cross-lane movement between steps.  g = exp(em - K) staged in LDS
// once per workgroup (cooperative, double-buffered).
// ---------------------------------------------------------------------------
__global__ __launch_bounds__(192, 6) void crf_scan(
    const float* __restrict__ em, const int* __restrict__ tags,
    const float* __restrict__ trans, float* __restrict__ out,
    float* __restrict__ ws)
{
    const int b   = blockIdx.x >> 4;
    const int s   = blockIdx.x & 15;
    const int tid = threadIdx.x;
    const int ct  = tid >> 6;          // wave = column tile 0..2
    const int ln  = tid & 63;
    const int q   = ln >> 4;           // 0..3
    const int c   = ln & 15;           // 0..15

    __shared__ __align__(16) float smem[2 * 384];   // 8 g-rows x 2 buffers

    const size_t bem = (size_t)b * T * L;
    const int t0 = 1 + SEG * s;
    const int t1 = (t0 + SEG < T) ? (t0 + SEG) : T;   // s=15 -> 127 steps

    // A fragments: all of E^T. A[m=c][k=4q+e], tile (rt, kt).
    v4s Af[3][3];
    #pragma unroll
    for (int rt = 0; rt < 3; ++rt)
        #pragma unroll
        for (int kt = 0; kt < 3; ++kt) {
            v4f e;
            #pragma unroll
            for (int ee = 0; ee < 4; ++ee)
                e[ee] = __expf(trans[(16 * kt + 4 * q + ee) * L + 16 * rt + c]);
            Af[rt][kt] = scale_pack(e, v4f{1.f, 1.f, 1.f, 1.f});
        }

    // State slice: B fragments Q[k=16*kt+4q+e][col=16*ct+c]. Init identity.
    v4s Bq[3];
    #pragma unroll
    for (int kt = 0; kt < 3; ++kt) {
        v2i d;
        int k0 = 16 * kt + 4 * q, col = 16 * ct + c;
        d.x = (k0 + 0 == col ? 0x3F80 : 0) | (k0 + 1 == col ? 0x3F800000 : 0);
        d.y = (k0 + 2 == col ? 0x3F80 : 0) | (k0 + 3 == col ? 0x3F800000 : 0);
        Bq[kt] = __builtin_bit_cast(v4s, d);
    }

    auto do_step = [&](const float* rowp) {
        v4f gv[3];
        #pragma unroll
        for (int rt = 0; rt < 3; ++rt)
            gv[rt] = *(const v4f*)(rowp + 16 * rt + 4 * q);
        v4f Cf[3];
        #pragma unroll
        for (int rt = 0; rt < 3; ++rt) {
            v4f acc = {0.f, 0.f, 0.f, 0.f};
            acc = MFMA16(Af[rt][0], Bq[0], acc);
            acc = MFMA16(Af[rt][1], Bq[1], acc);
            acc = MFMA16(Af[rt][2], Bq[2], acc);
            Cf[rt] = acc;
        }
        #pragma unroll
        for (int rt = 0; rt < 3; ++rt)
            Bq[rt] = scale_pack(Cf[rt], gv[rt]);   // row rt tile -> k tile rt
    };

    // stage g-rows t0..t0+7 into buffer 0 (cooperative: 2 floats/lane)
    {
        size_t gf = bem + (size_t)t0 * L;
        smem[tid]       = __expf(em[gf + tid]       - KNORM);
        smem[tid + 192] = __expf(em[gf + tid + 192] - KNORM);
        __syncthreads();
    }

    for (int bk = 0; bk < 16; ++bk) {
        const float* cur = smem + (bk & 1) * 384;
        float* nxt = smem + ((bk & 1) ^ 1) * 384;

        size_t gf = bem + (size_t)(t0 + 8 * (bk + 1)) * L;
        if (gf > (size_t)TOTALF - 384) gf = (size_t)TOTALF - 384;
        float stg0 = em[gf + tid];
        float stg1 = em[gf + tid + 192];

        #pragma unroll
        for (int k = 0; k < 8; ++k)
            if (t0 + 8 * bk + k < t1)            // workgroup-uniform guard
                do_step(cur + 48 * k);

        nxt[tid]       = __expf(stg0 - KNORM);
        nxt[tid + 192] = __expf(stg1 - KNORM);
        __syncthreads();
    }

    // store this wave's 16-col slice of Q, bf16 row-major [row*48+col]
    unsigned short* qs = (unsigned short*)ws + (size_t)(b * G + s) * 2304;
    #pragma unroll
    for (int kt = 0; kt < 3; ++kt) {
        v2i d = __builtin_bit_cast(v2i, Bq[kt]);
        int r0 = 16 * kt + 4 * q, col = 16 * ct + c;
        qs[(r0 + 0) * 48 + col] = (unsigned short)((unsigned)d.x & 0xffffu);
        qs[(r0 + 1) * 48 + col] = (unsigned short)((unsigned)d.x >> 16);
        qs[(r0 + 2) * 48 + col] = (unsigned short)((unsigned)d.y & 0xffffu);
        qs[(r0 + 3) * 48 + col] = (unsigned short)((unsigned)d.y >> 16);
    }

    // fused gold score for t in [128 s, 128 s + 128): one t per lane, tid<128
    const int* tg = tags + (size_t)b * T;
    float gp = 0.f;
    if (tid < 128) {
        int t = SEG * s + tid;
        int tag = tg[t];
        gp += em[bem + (size_t)t * L + tag];
        if (t < T - 1)  gp += trans[tag * L + tg[t + 1]];
        if (t == 0)     gp += trans[tag];
        if (t == T - 1) gp += trans[tag * L + (L - 1)];
    }
    #pragma unroll
    for (int off = 32; off; off >>= 1) gp += __shfl_xor(gp, off);
    __shared__ float red[3];
    if (ln == 0) red[ct] = gp;
    __syncthreads();
    if (tid == 0) atomicAdd(out, -(red[0] + red[1] + red[2]));
}

// ---------------------------------------------------------------------------
// Combine: per batch, u = alpha_0; for s: u = Q_s u (renormed, bf16 rows,
// next-segment register prefetch); Z_b = log(sum u_i E[i][end]) + 2047*K +
// accumulated renorm logs.  Lane l owns row l => no cross-lane reduce.
// ---------------------------------------------------------------------------
__global__ __launch_bounds__(64) void crf_combine(
    const float* __restrict__ em, const float* __restrict__ trans,
    const float* __restrict__ ws, float* __restrict__ out)
{
    const int b = blockIdx.x, l = threadIdx.x;
    const int lc = (l < L) ? l : (L - 1);

    __shared__ float us[64];

    const unsigned short* qb = (const unsigned short*)ws + (size_t)b * G * 2304;

    float u = (l < L) ? __expf(trans[l] + em[(size_t)b * T * L + l]) : 0.f;
    float logtot = 2047.0f * KNORM;

    uint4 pre[6];
    {
        const uint4* p = (const uint4*)(qb + lc * 48);
        #pragma unroll
        for (int ii = 0; ii < 6; ++ii) pre[ii] = p[ii];
    }

    for (int s = 0; s < G; ++s) {
        us[l] = u;
        uint4 cur[6];
        #pragma unroll
        for (int ii = 0; ii < 6; ++ii) cur[ii] = pre[ii];
        if (s + 1 < G) {
            const uint4* p = (const uint4*)(qb + (size_t)(s + 1) * 2304 + lc * 48);
            #pragma unroll
            for (int ii = 0; ii < 6; ++ii) pre[ii] = p[ii];
        }
        WAVE_SYNC();

        float acc = 0.f;
        #pragma unroll
        for (int ii = 0; ii < 6; ++ii) {
            unsigned w0 = cur[ii].x, w1 = cur[ii].y, w2 = cur[ii].z, w3 = cur[ii].w;
            int jj = ii * 8;
            acc = fmaf(__uint_as_float(w0 << 16),          us[jj + 0], acc);
            acc = fmaf(__uint_as_float(w0 & 0xffff0000u),  us[jj + 1], acc);
            acc = fmaf(__uint_as_float(w1 << 16),          us[jj + 2], acc);
            acc = fmaf(__uint_as_float(w1 & 0xffff0000u),  us[jj + 3], acc);
            acc = fmaf(__uint_as_float(w2 << 16),          us[jj + 4], acc);
            acc = fmaf(__uint_as_float(w2 & 0xffff0000u),  us[jj + 5], acc);
            acc = fmaf(__uint_as_float(w3 << 16),          us[jj + 6], acc);
            acc = fmaf(__uint_as_float(w3 & 0xffff0000u),  us[jj + 7], acc);
        }
        WAVE_SYNC();   // us reads done before next overwrite

        float r = __int_as_float(
            __builtin_amdgcn_readlane(__float_as_int(acc), 0));
        logtot += __logf(r);
        u = (l < L) ? acc * __builtin_amdgcn_rcpf(r) : 0.f;
    }

    float v = (l < L) ? u * __expf(trans[lc * L + (L - 1)]) : 0.f;
    #pragma unroll
    for (int off = 32; off; off >>= 1) v += __shfl_xor(v, off);
    if (l == 0) atomicAdd(out, logtot + __logf(v));
}

extern "C" void kernel_launch(void* const* d_in, const int* in_sizes, int n_in,
                              void* d_out, int out_size, void* d_ws, size_t ws_size,
                              hipStream_t stream) {
    const float* em    = (const float*)d_in[0];   // (B, T, L) f32
    const int*   tags  = (const int*)  d_in[1];   // (B, T) i32
    const float* trans = (const float*)d_in[2];   // (L, L) f32
    float* out = (float*)d_out;
    float* ws  = (float*)d_ws;                    // 4096 * 2304 bf16 = 18.9 MB

    (void)hipMemsetAsync(out, 0, sizeof(float), stream);
    crf_scan   <<<B * G, 192, 0, stream>>>(em, tags, trans, out, ws);
    crf_combine<<<B,      64, 0, stream>>>(em, trans, ws, out);
}